// Round 2
// baseline (508.018 us; speedup 1.0000x reference)
//
#include <hip/hip_runtime.h>
#include <math.h>

typedef __bf16 bf8_t __attribute__((ext_vector_type(8)));
typedef short  s8_t  __attribute__((ext_vector_type(8)));
typedef float  f4_t  __attribute__((ext_vector_type(4)));

#define CIN   128
#define COUT  128
#define RES   256
#define WDIM  512
#define NCOL  136   // fallback kernel: staged halo columns
#define PROWS 258   // padded rows: -1 .. 256
#define PCOLS 264   // padded cols: -4 .. 259

// round-to-nearest-even f32 -> bf16 bits (inputs finite, no NaN handling)
static __device__ __forceinline__ unsigned short f2bf(float f) {
    unsigned u = __float_as_uint(f);
    unsigned r = (u + 0x7fffu + ((u >> 16) & 1u)) >> 16;
    return (unsigned short)r;
}

// ---- prep 1: styles[b][i] = (w[b]·affine_w[i])/sqrt(512) + affine_b[i] ----
__global__ void k_styles(const float* __restrict__ w, const float* __restrict__ aw,
                         const float* __restrict__ ab, float* __restrict__ styles) {
    int t = blockIdx.x * 256 + threadIdx.x;      // 1024 threads: (b, i)
    int b = t >> 7, i = t & 127;
    const float4* wr = (const float4*)(w + b * WDIM);
    const float4* ar = (const float4*)(aw + i * WDIM);
    float s = 0.f;
    for (int j = 0; j < WDIM / 4; ++j) {
        float4 a = ar[j], c = wr[j];
        s += a.x * c.x + a.y * c.y + a.z * c.z + a.w * c.w;
    }
    styles[t] = s * 0.04419417382415922f + ab[i];   // 1/sqrt(512)
}

// ---- prep 2: w2[o][i] = sum_k weight^2 ; wb[(kh*3+kw)][o][i] = bf16(weight) ----
__global__ void k_wprep(const float* __restrict__ wt, float* __restrict__ w2,
                        unsigned short* __restrict__ wb) {
    int t = blockIdx.x * 256 + threadIdx.x;      // 16384 threads: (o, i)
    int o = t >> 7, i = t & 127;
    float s = 0.f;
    for (int kk = 0; kk < 9; ++kk) {
        float v = wt[(o * CIN + i) * 9 + kk];
        s += v * v;
        wb[(kk * COUT + o) * CIN + i] = f2bf(v);
    }
    w2[o * CIN + i] = s;
}

// ---- prep 3: dcoef[b][o] = 1/sqrt(sum_i w2[o][i]*styles[b][i]^2 + 1e-8) ----
__global__ void k_dcoef(const float* __restrict__ w2, const float* __restrict__ styles,
                        float* __restrict__ dcoef) {
    int t = blockIdx.x * 256 + threadIdx.x;      // 1024 threads: (b, o)
    int b = t >> 7, o = t & 127;
    float s = 0.f;
    for (int i = 0; i < CIN; ++i) {
        float st = styles[b * CIN + i];
        s += w2[o * CIN + i] * st * st;
    }
    dcoef[t] = 1.0f / sqrtf(s + 1e-8f);
}

// ---- prep 4: modulated bf16 x in MFMA-native padded layout ----
// xb flat group index t = ((b*16+cig)*PROWS + pr)*PCOLS + pc ; group = 8 ch = 16B
// pr = row+1 (rows -1..256), pc = col+4 (cols -4..259); pads are zero.
__global__ __launch_bounds__(256) void k_prep_x(
    const float* __restrict__ x, const float* __restrict__ styles,
    unsigned short* __restrict__ xb) {
    int t = blockIdx.x * 256 + threadIdx.x;      // 8*16*258*264 = 8,718,336 groups
    int pc = t % PCOLS;
    int r1 = t / PCOLS;
    int pr = r1 % PROWS;
    int bc = r1 / PROWS;                         // b*16 + cig
    int b = bc >> 4, cig = bc & 15;
    int r = pr - 1, c = pc - 4;
    unsigned short v[8];
    if ((r >= 0) & (r < RES) & (c >= 0) & (c < RES)) {
        const float* xp = x + (((size_t)b * CIN + cig * 8) * RES + r) * RES + c;
        const float* st = styles + b * CIN + cig * 8;
        #pragma unroll
        for (int j = 0; j < 8; ++j)
            v[j] = f2bf(xp[(size_t)j * RES * RES] * st[j]);
    } else {
        #pragma unroll
        for (int j = 0; j < 8; ++j) v[j] = 0;
    }
    *(s8_t*)(xb + (size_t)t * 8) = *(const s8_t*)v;   // 16B/lane, wave-contiguous
}

// ---- main: 128 Cout x 128 px tile; all operands direct from global (L1/L2),
//      no LDS staging, no main-loop barriers, 4 blocks/CU ----
__global__ __launch_bounds__(256, 4) void k_conv2(
    const float* __restrict__ noise, const float* __restrict__ nstrp,
    const float* __restrict__ bias, const float* __restrict__ dcoef,
    const unsigned short* __restrict__ wb, const unsigned short* __restrict__ xb,
    float* __restrict__ out) {

    __shared__ float s_dc[COUT], s_bias[COUT];   // 1 KB total

    int blk0 = blockIdx.x;
    int blk  = (blk0 & 7) * 512 + (blk0 >> 3);   // XCD swizzle: each XCD streams one b
    int b   = blk >> 9;
    int rem = blk & 511;
    int h0  = rem >> 1;
    int w0  = (rem & 1) << 7;

    int tid = threadIdx.x;
    if (tid < 128) s_dc[tid] = dcoef[b * COUT + tid];
    else           s_bias[tid - 128] = bias[tid - 128];
    __syncthreads();                             // only barrier in the kernel

    int lane = tid & 63, wave = tid >> 6;
    int mbase = (wave & 1) * 64;                 // co block of this wave
    int nbase = (wave >> 1) * 64;                // px block of this wave
    int l15 = lane & 15, quad = lane >> 4;

    // per-lane A base: row (mbase+l15), col (quad*8); + mt*16*CIN, + kk*COUT*CIN, + ks*32
    const unsigned short* arow = wb + (mbase + l15) * CIN + quad * 8;
    // per-lane B base: cig=quad plane, padded col (w0+nbase+l15+3); + ks*4 planes,
    //                  + pr rows, + (nt*16+kw) cols
    const unsigned short* brow = xb
        + ((size_t)b * 16 + quad) * ((size_t)PROWS * PCOLS * 8)
        + (size_t)(w0 + nbase + l15 + 3) * 8;

    f4_t acc[4][4];
    #pragma unroll
    for (int m = 0; m < 4; ++m)
        #pragma unroll
        for (int n = 0; n < 4; ++n)
            acc[m][n] = (f4_t)0.f;

    #pragma unroll
    for (int kh = 0; kh < 3; ++kh) {
        int pr = h0 + kh;                        // padded row index
        #pragma unroll
        for (int kw = 0; kw < 3; ++kw) {
            const unsigned short* ak = arow + (kh * 3 + kw) * COUT * CIN;
            const unsigned short* bk = brow + ((size_t)pr * PCOLS + kw) * 8;
            #pragma unroll
            for (int ks = 0; ks < 4; ++ks) {
                s8_t af[4], bfg[4];
                #pragma unroll
                for (int mt = 0; mt < 4; ++mt)
                    af[mt] = *(const s8_t*)(ak + mt * 16 * CIN + ks * 32);
                const unsigned short* bp = bk + (size_t)ks * 4 * PROWS * PCOLS * 8;
                #pragma unroll
                for (int nt = 0; nt < 4; ++nt)
                    bfg[nt] = *(const s8_t*)(bp + nt * 16 * 8);
                #pragma unroll
                for (int mt = 0; mt < 4; ++mt)
                    #pragma unroll
                    for (int nt = 0; nt < 4; ++nt)
                        acc[mt][nt] = __builtin_amdgcn_mfma_f32_16x16x32_bf16(
                            __builtin_bit_cast(bf8_t, af[mt]),
                            __builtin_bit_cast(bf8_t, bfg[nt]),
                            acc[mt][nt], 0, 0, 0);
            }
        }
    }

    // ---- epilogue: demod, noise, bias, lrelu, gain, clamp ----
    float nstr = nstrp[0];
    const float* nrow = noise + h0 * RES + w0;
    float nz[4];
    #pragma unroll
    for (int nt = 0; nt < 4; ++nt)
        nz[nt] = nrow[nbase + nt * 16 + l15] * nstr;

    float* orow = out + (size_t)b * COUT * RES * RES + h0 * RES + w0;
    #pragma unroll
    for (int mt = 0; mt < 4; ++mt) {
        #pragma unroll
        for (int rg = 0; rg < 4; ++rg) {
            int co = mbase + mt * 16 + quad * 4 + rg;   // C/D: row = quad*4+reg
            float dc = s_dc[co], bi = s_bias[co];
            #pragma unroll
            for (int nt = 0; nt < 4; ++nt) {
                int px = nbase + nt * 16 + l15;          // C/D: col = lane&15
                float v = acc[mt][nt][rg] * dc + nz[nt] + bi;
                v = (v >= 0.f) ? v : 0.2f * v;
                v *= 1.4142135623730951f;                // sqrt(2) gain
                v = fminf(fmaxf(v, -256.f), 256.f);
                orow[(size_t)co * RES * RES + px] = v;
            }
        }
    }
}

// ---- fallback (old fused kernel) if workspace can't hold xb ----
__global__ __launch_bounds__(256) void k_conv_fb(
    const float* __restrict__ x, const float* __restrict__ noise,
    const float* __restrict__ nstrp, const float* __restrict__ bias,
    const float* __restrict__ styles, const float* __restrict__ dcoef,
    const unsigned short* __restrict__ wb, float* __restrict__ out) {

    __shared__ s8_t xs[16 * NCOL];
    __shared__ float s_sty[CIN], s_dc[COUT], s_bias[COUT];

    int blk = blockIdx.x;
    int b   = blk >> 9;
    int rem = blk & 511;
    int h0  = rem >> 1;
    int w0  = (rem & 1) << 7;

    int tid = threadIdx.x;
    if (tid < 128) {
        s_sty[tid] = styles[b * CIN + tid];
    } else {
        s_dc[tid - 128]   = dcoef[b * COUT + tid - 128];
        s_bias[tid - 128] = bias[tid - 128];
    }

    int lane = tid & 63, wave = tid >> 6;
    int mbase = (wave & 1) * 64;
    int nbase = (wave >> 1) * 64;
    int l15 = lane & 15, quad = lane >> 4;

    f4_t acc[4][4];
    for (int m = 0; m < 4; ++m)
        for (int n = 0; n < 4; ++n)
            acc[m][n] = (f4_t)0.f;

    for (int kh = 0; kh < 3; ++kh) {
        int r = h0 - 1 + kh;
        bool rowok = (r >= 0) && (r < RES);
        int rc = rowok ? r : 0;
        const float* xrow = x + ((size_t)b * CIN * RES + rc) * RES;

        __syncthreads();
        for (int it = 0; it < 9; ++it) {
            int g = it * 256 + tid;
            if (g < 16 * NCOL) {
                int cig = g / NCOL, col = g - cig * NCOL;
                int wcol = w0 - 4 + col;
                bool ok = rowok && (wcol >= 0) && (wcol < RES);
                s8_t v8;
                for (int j = 0; j < 8; ++j) {
                    int ci = cig * 8 + j;
                    float v = ok ? xrow[(size_t)ci * RES * RES + wcol] * s_sty[ci] : 0.f;
                    v8[j] = (short)f2bf(v);
                }
                xs[g] = v8;
            }
        }
        __syncthreads();

        for (int kw = 0; kw < 3; ++kw) {
            const unsigned short* wbk = wb + (kh * 3 + kw) * COUT * CIN;
            for (int ks = 0; ks < 4; ++ks) {
                s8_t af[4], bfg[4];
                for (int mt = 0; mt < 4; ++mt) {
                    int co = mbase + mt * 16 + l15;
                    af[mt] = *(const s8_t*)(wbk + co * CIN + ks * 32 + quad * 8);
                }
                int cig = ks * 4 + quad;
                for (int nt = 0; nt < 4; ++nt) {
                    int col = nbase + nt * 16 + l15 + kw + 3;
                    bfg[nt] = xs[cig * NCOL + col];
                }
                for (int mt = 0; mt < 4; ++mt)
                    for (int nt = 0; nt < 4; ++nt)
                        acc[mt][nt] = __builtin_amdgcn_mfma_f32_16x16x32_bf16(
                            __builtin_bit_cast(bf8_t, af[mt]),
                            __builtin_bit_cast(bf8_t, bfg[nt]),
                            acc[mt][nt], 0, 0, 0);
            }
        }
    }

    float nstr = nstrp[0];
    const float* nrow = noise + h0 * RES + w0;
    float nz[4];
    for (int nt = 0; nt < 4; ++nt)
        nz[nt] = nrow[nbase + nt * 16 + l15] * nstr;

    float* orow = out + (size_t)b * COUT * RES * RES + h0 * RES + w0;
    for (int mt = 0; mt < 4; ++mt) {
        for (int rg = 0; rg < 4; ++rg) {
            int co = mbase + mt * 16 + quad * 4 + rg;
            float dc = s_dc[co], bi = s_bias[co];
            for (int nt = 0; nt < 4; ++nt) {
                int px = nbase + nt * 16 + l15;
                float v = acc[mt][nt][rg] * dc + nz[nt] + bi;
                v = (v >= 0.f) ? v : 0.2f * v;
                v *= 1.4142135623730951f;
                v = fminf(fmaxf(v, -256.f), 256.f);
                orow[(size_t)co * RES * RES + px] = v;
            }
        }
    }
}

extern "C" void kernel_launch(void* const* d_in, const int* in_sizes, int n_in,
                              void* d_out, int out_size, void* d_ws, size_t ws_size,
                              hipStream_t stream) {
    const float* x     = (const float*)d_in[0];
    const float* w     = (const float*)d_in[1];
    const float* aw    = (const float*)d_in[2];
    const float* ab    = (const float*)d_in[3];
    const float* wt    = (const float*)d_in[4];
    const float* noise = (const float*)d_in[5];
    const float* nstr  = (const float*)d_in[6];
    const float* bias  = (const float*)d_in[7];
    // d_in[8] = noise_mode (reference adds const noise unconditionally)

    float* ws     = (float*)d_ws;
    float* styles = ws;                    // [8][128] f32
    float* dcoef  = ws + 1024;             // [8][128] f32
    float* w2     = ws + 2048;             // [128][128] f32
    unsigned short* wb = (unsigned short*)(ws + 2048 + 16384);  // [9][128][128] bf16
    const size_t xb_off   = 368640;        // bytes: 4K+4K+64K+288K
    const size_t xb_bytes = (size_t)8 * 16 * PROWS * PCOLS * 16;  // 139,493,376
    unsigned short* xb = (unsigned short*)((char*)d_ws + xb_off);
    float* out = (float*)d_out;

    hipLaunchKernelGGL(k_styles, dim3(4),  dim3(256), 0, stream, w, aw, ab, styles);
    hipLaunchKernelGGL(k_wprep,  dim3(64), dim3(256), 0, stream, wt, w2, wb);
    hipLaunchKernelGGL(k_dcoef,  dim3(4),  dim3(256), 0, stream, w2, styles, dcoef);

    if (ws_size >= xb_off + xb_bytes) {
        hipLaunchKernelGGL(k_prep_x, dim3(34056), dim3(256), 0, stream, x, styles, xb);
        hipLaunchKernelGGL(k_conv2,  dim3(4096),  dim3(256), 0, stream,
                           noise, nstr, bias, dcoef, wb, xb, out);
    } else {
        hipLaunchKernelGGL(k_conv_fb, dim3(4096), dim3(256), 0, stream,
                           x, noise, nstr, bias, styles, dcoef, wb, out);
    }
}

// Round 3
// 439.183 us; speedup vs baseline: 1.1567x; 1.1567x over previous
//
#include <hip/hip_runtime.h>
#include <math.h>

typedef __bf16 bf8_t __attribute__((ext_vector_type(8)));
typedef short  s8_t  __attribute__((ext_vector_type(8)));
typedef float  f4_t  __attribute__((ext_vector_type(4)));

#define CIN   128
#define COUT  128
#define RES   256
#define WDIM  512
#define NCOL  136   // fallback kernel: staged halo columns
#define PROWS 258   // padded rows: -1 .. 256
#define PCOLS 264   // padded cols: -4 .. 259
#define SCOL  132   // staged cols per half-row buffer: w0-2 .. w0+129
#define SSTR  134   // LDS plane stride in 16B groups (2144 B: quad phases 0,24,16,8)

// round-to-nearest-even f32 -> bf16 bits (inputs finite, no NaN handling)
static __device__ __forceinline__ unsigned short f2bf(float f) {
    unsigned u = __float_as_uint(f);
    unsigned r = (u + 0x7fffu + ((u >> 16) & 1u)) >> 16;
    return (unsigned short)r;
}

// ---- prep 1: styles[b][i] = (w[b]·affine_w[i])/sqrt(512) + affine_b[i] ----
__global__ void k_styles(const float* __restrict__ w, const float* __restrict__ aw,
                         const float* __restrict__ ab, float* __restrict__ styles) {
    int t = blockIdx.x * 256 + threadIdx.x;      // 1024 threads: (b, i)
    int b = t >> 7, i = t & 127;
    const float4* wr = (const float4*)(w + b * WDIM);
    const float4* ar = (const float4*)(aw + i * WDIM);
    float s = 0.f;
    for (int j = 0; j < WDIM / 4; ++j) {
        float4 a = ar[j], c = wr[j];
        s += a.x * c.x + a.y * c.y + a.z * c.z + a.w * c.w;
    }
    styles[t] = s * 0.04419417382415922f + ab[i];   // 1/sqrt(512)
}

// ---- prep 2: w2[o][i] = sum_k weight^2 ; wb[(kh*3+kw)][o][i] = bf16(weight) ----
__global__ void k_wprep(const float* __restrict__ wt, float* __restrict__ w2,
                        unsigned short* __restrict__ wb) {
    int t = blockIdx.x * 256 + threadIdx.x;      // 16384 threads: (o, i)
    int o = t >> 7, i = t & 127;
    float s = 0.f;
    for (int kk = 0; kk < 9; ++kk) {
        float v = wt[(o * CIN + i) * 9 + kk];
        s += v * v;
        wb[(kk * COUT + o) * CIN + i] = f2bf(v);
    }
    w2[o * CIN + i] = s;
}

// ---- prep 3: dcoef[b][o] = 1/sqrt(sum_i w2[o][i]*styles[b][i]^2 + 1e-8) ----
__global__ void k_dcoef(const float* __restrict__ w2, const float* __restrict__ styles,
                        float* __restrict__ dcoef) {
    int t = blockIdx.x * 256 + threadIdx.x;      // 1024 threads: (b, o)
    int b = t >> 7, o = t & 127;
    float s = 0.f;
    for (int i = 0; i < CIN; ++i) {
        float st = styles[b * CIN + i];
        s += w2[o * CIN + i] * st * st;
    }
    dcoef[t] = 1.0f / sqrtf(s + 1e-8f);
}

// ---- prep 4: modulated bf16 x in MFMA-native padded layout ----
// xb flat group index t = ((b*16+cig)*PROWS + pr)*PCOLS + pc ; group = 8 ch = 16B
// pr = row+1 (rows -1..256), pc = col+4 (cols -4..259); pads are zero.
__global__ __launch_bounds__(256) void k_prep_x(
    const float* __restrict__ x, const float* __restrict__ styles,
    unsigned short* __restrict__ xb) {
    int t = blockIdx.x * 256 + threadIdx.x;      // 8*16*258*264 = 8,718,336 groups
    int pc = t % PCOLS;
    int r1 = t / PCOLS;
    int pr = r1 % PROWS;
    int bc = r1 / PROWS;                         // b*16 + cig
    int b = bc >> 4, cig = bc & 15;
    int r = pr - 1, c = pc - 4;
    unsigned short v[8];
    if ((r >= 0) & (r < RES) & (c >= 0) & (c < RES)) {
        const float* xp = x + (((size_t)b * CIN + cig * 8) * RES + r) * RES + c;
        const float* st = styles + b * CIN + cig * 8;
        #pragma unroll
        for (int j = 0; j < 8; ++j)
            v[j] = f2bf(xp[(size_t)j * RES * RES] * st[j]);
    } else {
        #pragma unroll
        for (int j = 0; j < 8; ++j) v[j] = 0;
    }
    *(s8_t*)(xb + (size_t)t * 8) = *(const s8_t*)v;   // 16B/lane, wave-contiguous
}

// ---- main: 128 Cout x 128 px tile; 6 half-row phases, 3-deep LDS ring,
//      reg-staged global->LDS (T14), conflict-free plane stride, 3 blocks/CU ----
__global__ __launch_bounds__(256, 3) void k_conv3(
    const float* __restrict__ noise, const float* __restrict__ nstrp,
    const float* __restrict__ bias, const float* __restrict__ dcoef,
    const unsigned short* __restrict__ wb, const unsigned short* __restrict__ xb,
    float* __restrict__ out) {

    __shared__ s8_t xs[3][8][SSTR];              // 3 x 17152 B ring
    __shared__ float s_dc[COUT], s_bias[COUT];   // 1 KB

    int blk0 = blockIdx.x;
    int blk  = (blk0 & 7) * 512 + (blk0 >> 3);   // XCD swizzle: each XCD streams one b
    int b   = blk >> 9;
    int rem = blk & 511;
    int h0  = rem >> 1;
    int w0  = (rem & 1) << 7;

    int tid = threadIdx.x;
    if (tid < 128) s_dc[tid] = dcoef[b * COUT + tid];
    else           s_bias[tid - 128] = bias[tid - 128];

    int lane = tid & 63, wave = tid >> 6;
    int mbase = (wave & 1) * 64;                 // co block of this wave
    int nbase = (wave >> 1) * 64;                // px block of this wave
    int l15 = lane & 15, quad = lane >> 4;

    const unsigned short* xbb = xb + (size_t)b * ((size_t)16 * PROWS * PCOLS * 8);
    const unsigned short* arow = wb + (mbase + l15) * CIN + quad * 8;

    f4_t acc[4][4];
    #pragma unroll
    for (int m = 0; m < 4; ++m)
        #pragma unroll
        for (int n = 0; n < 4; ++n)
            acc[m][n] = (f4_t)0.f;

    // per-wave stage: 2 cig planes x SCOL cols = 264 groups -> 5 loads (last 8 lanes)
    s8_t R[5];
    // hp: 0..5 = (kh = hp>>1, cig-half = hp&1). Row pr = h0 + kh (padded).
    auto ld = [&](int hp) {
        int pr = h0 + (hp >> 1);
        int cb = (hp & 1) * 8 + wave * 2;        // global cig of plane 0 of this wave
        #pragma unroll
        for (int li = 0; li < 5; ++li) {
            int g = li * 64 + lane;
            if (g < 2 * SCOL) {
                int pl = (g >= SCOL) ? 1 : 0;
                int cc = g - pl * SCOL;
                const unsigned short* s = xbb
                    + (((size_t)(cb + pl) * PROWS + pr) * PCOLS + (w0 + 2 + cc)) * 8;
                R[li] = *(const s8_t*)s;
            }
        }
    };
    auto st = [&](int buf) {
        int cb = wave * 2;                       // in-buffer plane of this wave
        #pragma unroll
        for (int li = 0; li < 5; ++li) {
            int g = li * 64 + lane;
            if (g < 2 * SCOL) {
                int pl = (g >= SCOL) ? 1 : 0;
                int cc = g - pl * SCOL;
                xs[buf][cb + pl][cc] = R[li];
            }
        }
    };

    // prologue: fill ring with phases 0,1; load phase 2 into regs
    ld(0); st(0);
    ld(1); st(1);
    ld(2);
    __syncthreads();

    #pragma unroll
    for (int hp = 0; hp < 6; ++hp) {
        int buf = hp % 3;
        int kh = hp >> 1;
        // compute this half: 3 kw x 2 ks = 6 steps x 16 MFMA
        #pragma unroll
        for (int kw = 0; kw < 3; ++kw) {
            const unsigned short* ak = arow + (kh * 3 + kw) * COUT * CIN;
            #pragma unroll
            for (int ks2 = 0; ks2 < 2; ++ks2) {
                int ks = (hp & 1) * 2 + ks2;
                s8_t af[4], bfg[4];
                #pragma unroll
                for (int mt = 0; mt < 4; ++mt)
                    af[mt] = *(const s8_t*)(ak + mt * 16 * CIN + ks * 32);
                #pragma unroll
                for (int nt = 0; nt < 4; ++nt)
                    bfg[nt] = xs[buf][ks2 * 4 + quad][nbase + nt * 16 + l15 + kw + 1];
                __builtin_amdgcn_s_setprio(1);
                #pragma unroll
                for (int mt = 0; mt < 4; ++mt)
                    #pragma unroll
                    for (int nt = 0; nt < 4; ++nt)
                        acc[mt][nt] = __builtin_amdgcn_mfma_f32_16x16x32_bf16(
                            __builtin_bit_cast(bf8_t, af[mt]),
                            __builtin_bit_cast(bf8_t, bfg[nt]),
                            acc[mt][nt], 0, 0, 0);
                __builtin_amdgcn_s_setprio(0);
            }
        }
        __syncthreads();                         // ring slot (hp+2)%3 now writable
        if (hp + 2 <= 5) {
            st((hp + 2) % 3);                    // data(hp+2) -> LDS
            if (hp + 3 <= 5) ld(hp + 3);         // issue loads for data(hp+3)
        }
    }

    // ---- epilogue: demod, noise, bias, lrelu, gain, clamp ----
    float nstr = nstrp[0];
    const float* nrow = noise + h0 * RES + w0;
    float nz[4];
    #pragma unroll
    for (int nt = 0; nt < 4; ++nt)
        nz[nt] = nrow[nbase + nt * 16 + l15] * nstr;

    float* orow = out + (size_t)b * COUT * RES * RES + h0 * RES + w0;
    #pragma unroll
    for (int mt = 0; mt < 4; ++mt) {
        #pragma unroll
        for (int rg = 0; rg < 4; ++rg) {
            int co = mbase + mt * 16 + quad * 4 + rg;   // C/D: row = quad*4+reg
            float dc = s_dc[co], bi = s_bias[co];
            #pragma unroll
            for (int nt = 0; nt < 4; ++nt) {
                int px = nbase + nt * 16 + l15;          // C/D: col = lane&15
                float v = acc[mt][nt][rg] * dc + nz[nt] + bi;
                v = (v >= 0.f) ? v : 0.2f * v;
                v *= 1.4142135623730951f;                // sqrt(2) gain
                v = fminf(fmaxf(v, -256.f), 256.f);
                orow[(size_t)co * RES * RES + px] = v;
            }
        }
    }
}

// ---- fallback (old fused kernel) if workspace can't hold xb ----
__global__ __launch_bounds__(256) void k_conv_fb(
    const float* __restrict__ x, const float* __restrict__ noise,
    const float* __restrict__ nstrp, const float* __restrict__ bias,
    const float* __restrict__ styles, const float* __restrict__ dcoef,
    const unsigned short* __restrict__ wb, float* __restrict__ out) {

    __shared__ s8_t xs[16 * NCOL];
    __shared__ float s_sty[CIN], s_dc[COUT], s_bias[COUT];

    int blk = blockIdx.x;
    int b   = blk >> 9;
    int rem = blk & 511;
    int h0  = rem >> 1;
    int w0  = (rem & 1) << 7;

    int tid = threadIdx.x;
    if (tid < 128) {
        s_sty[tid] = styles[b * CIN + tid];
    } else {
        s_dc[tid - 128]   = dcoef[b * COUT + tid - 128];
        s_bias[tid - 128] = bias[tid - 128];
    }

    int lane = tid & 63, wave = tid >> 6;
    int mbase = (wave & 1) * 64;
    int nbase = (wave >> 1) * 64;
    int l15 = lane & 15, quad = lane >> 4;

    f4_t acc[4][4];
    for (int m = 0; m < 4; ++m)
        for (int n = 0; n < 4; ++n)
            acc[m][n] = (f4_t)0.f;

    for (int kh = 0; kh < 3; ++kh) {
        int r = h0 - 1 + kh;
        bool rowok = (r >= 0) && (r < RES);
        int rc = rowok ? r : 0;
        const float* xrow = x + ((size_t)b * CIN * RES + rc) * RES;

        __syncthreads();
        for (int it = 0; it < 9; ++it) {
            int g = it * 256 + tid;
            if (g < 16 * NCOL) {
                int cig = g / NCOL, col = g - cig * NCOL;
                int wcol = w0 - 4 + col;
                bool ok = rowok && (wcol >= 0) && (wcol < RES);
                s8_t v8;
                for (int j = 0; j < 8; ++j) {
                    int ci = cig * 8 + j;
                    float v = ok ? xrow[(size_t)ci * RES * RES + wcol] * s_sty[ci] : 0.f;
                    v8[j] = (short)f2bf(v);
                }
                xs[g] = v8;
            }
        }
        __syncthreads();

        for (int kw = 0; kw < 3; ++kw) {
            const unsigned short* wbk = wb + (kh * 3 + kw) * COUT * CIN;
            for (int ks = 0; ks < 4; ++ks) {
                s8_t af[4], bfg[4];
                for (int mt = 0; mt < 4; ++mt) {
                    int co = mbase + mt * 16 + l15;
                    af[mt] = *(const s8_t*)(wbk + co * CIN + ks * 32 + quad * 8);
                }
                int cig = ks * 4 + quad;
                for (int nt = 0; nt < 4; ++nt) {
                    int col = nbase + nt * 16 + l15 + kw + 3;
                    bfg[nt] = xs[cig * NCOL + col];
                }
                for (int mt = 0; mt < 4; ++mt)
                    for (int nt = 0; nt < 4; ++nt)
                        acc[mt][nt] = __builtin_amdgcn_mfma_f32_16x16x32_bf16(
                            __builtin_bit_cast(bf8_t, af[mt]),
                            __builtin_bit_cast(bf8_t, bfg[nt]),
                            acc[mt][nt], 0, 0, 0);
            }
        }
    }

    float nstr = nstrp[0];
    const float* nrow = noise + h0 * RES + w0;
    float nz[4];
    for (int nt = 0; nt < 4; ++nt)
        nz[nt] = nrow[nbase + nt * 16 + l15] * nstr;

    float* orow = out + (size_t)b * COUT * RES * RES + h0 * RES + w0;
    for (int mt = 0; mt < 4; ++mt) {
        for (int rg = 0; rg < 4; ++rg) {
            int co = mbase + mt * 16 + quad * 4 + rg;
            float dc = s_dc[co], bi = s_bias[co];
            for (int nt = 0; nt < 4; ++nt) {
                int px = nbase + nt * 16 + l15;
                float v = acc[mt][nt][rg] * dc + nz[nt] + bi;
                v = (v >= 0.f) ? v : 0.2f * v;
                v *= 1.4142135623730951f;
                v = fminf(fmaxf(v, -256.f), 256.f);
                orow[(size_t)co * RES * RES + px] = v;
            }
        }
    }
}

extern "C" void kernel_launch(void* const* d_in, const int* in_sizes, int n_in,
                              void* d_out, int out_size, void* d_ws, size_t ws_size,
                              hipStream_t stream) {
    const float* x     = (const float*)d_in[0];
    const float* w     = (const float*)d_in[1];
    const float* aw    = (const float*)d_in[2];
    const float* ab    = (const float*)d_in[3];
    const float* wt    = (const float*)d_in[4];
    const float* noise = (const float*)d_in[5];
    const float* nstr  = (const float*)d_in[6];
    const float* bias  = (const float*)d_in[7];
    // d_in[8] = noise_mode (reference adds const noise unconditionally)

    float* ws     = (float*)d_ws;
    float* styles = ws;                    // [8][128] f32
    float* dcoef  = ws + 1024;             // [8][128] f32
    float* w2     = ws + 2048;             // [128][128] f32
    unsigned short* wb = (unsigned short*)(ws + 2048 + 16384);  // [9][128][128] bf16
    const size_t xb_off   = 368640;        // bytes: 4K+4K+64K+288K
    const size_t xb_bytes = (size_t)8 * 16 * PROWS * PCOLS * 16;  // 139,493,376
    unsigned short* xb = (unsigned short*)((char*)d_ws + xb_off);
    float* out = (float*)d_out;

    hipLaunchKernelGGL(k_styles, dim3(4),  dim3(256), 0, stream, w, aw, ab, styles);
    hipLaunchKernelGGL(k_wprep,  dim3(64), dim3(256), 0, stream, wt, w2, wb);
    hipLaunchKernelGGL(k_dcoef,  dim3(4),  dim3(256), 0, stream, w2, styles, dcoef);

    if (ws_size >= xb_off + xb_bytes) {
        hipLaunchKernelGGL(k_prep_x, dim3(34056), dim3(256), 0, stream, x, styles, xb);
        hipLaunchKernelGGL(k_conv3,  dim3(4096),  dim3(256), 0, stream,
                           noise, nstr, bias, dcoef, wb, xb, out);
    } else {
        hipLaunchKernelGGL(k_conv_fb, dim3(4096), dim3(256), 0, stream,
                           x, noise, nstr, bias, styles, dcoef, wb, out);
    }
}